// Round 7
// baseline (759.609 us; speedup 1.0000x reference)
//
#include <hip/hip_runtime.h>
#include <hip/hip_bf16.h>

#define NN 50000
#define EE 640000
#define LN_EPS 1e-5f
#define KD 272              // extended K (256 feat + deg + md + 1 + 13 zero pad)
#define KB 544              // bytes per feat/W1 row (KD*2)
#define NBK2 782            // buckets of 64 nodes (src >> 6)
#define CH 4096             // edges per binning block

typedef __bf16 bf16x8 __attribute__((ext_vector_type(8)));
typedef float f32x16 __attribute__((ext_vector_type(16)));

static __device__ __forceinline__ unsigned short f2bf(float f) {
    return __builtin_bit_cast(unsigned short, (__bf16)f);
}
static __device__ __forceinline__ float bflo(unsigned int u) {   // low bf16 of dword
    return __builtin_bit_cast(float, u << 16);
}
static __device__ __forceinline__ float bfhi(unsigned int u) {   // high bf16 of dword
    return __builtin_bit_cast(float, u & 0xffff0000u);
}

// ---- cast x to bf16 (gather source)
__global__ __launch_bounds__(256) void cast_x(const float* __restrict__ x,
                                              unsigned short* __restrict__ xbf) {
    int i = blockIdx.x * 256 + threadIdx.x;          // 8 elems per thread, 3125 blocks exact
    const float4* s = (const float4*)x + (size_t)i * 2;
    float4 a = s[0], b = s[1];
    unsigned short o[8] = { f2bf(a.x), f2bf(a.y), f2bf(a.z), f2bf(a.w),
                            f2bf(b.x), f2bf(b.y), f2bf(b.z), f2bf(b.w) };
    *(uint4*)(xbf + (size_t)i * 8) = *(const uint4*)o;
}

// ---- weight prep: W1Te[c][k] (512 x 272): k<256 = W1[k][c]; 256=W1[256][c]; 257=W1[257][c];
//      258=b1[c]; 259..271=0.  W2T[c][k] (128 x 512) = W2[k][c].
__global__ __launch_bounds__(256) void prep_weights(const float* __restrict__ W1,
                                                    const float* __restrict__ b1,
                                                    const float* __restrict__ W2,
                                                    unsigned short* __restrict__ W1Te,
                                                    unsigned short* __restrict__ W2T) {
    int b = blockIdx.x, tid = threadIdx.x;
    if (b < 512) {
        W1Te[(size_t)b * KD + tid] = f2bf(W1[(size_t)tid * 512 + b]);
        if (tid < 16) {
            float v = 0.f;
            if (tid == 0) v = W1[256 * 512 + b];
            else if (tid == 1) v = W1[257 * 512 + b];
            else if (tid == 2) v = b1[b];
            W1Te[(size_t)b * KD + 256 + tid] = f2bf(v);
        }
    } else {
        int c = b - 512;
        W2T[(size_t)c * 512 + tid]       = f2bf(W2[(size_t)tid * 128 + c]);
        W2T[(size_t)c * 512 + 256 + tid] = f2bf(W2[(size_t)(256 + tid) * 128 + c]);
    }
}

// ---- per-bucket (64 nodes) edge counts from degrees; wave per bucket
__global__ __launch_bounds__(256) void hist_kernel(const float* __restrict__ degrees,
                                                   int* __restrict__ bcnt) {
    int tid = threadIdx.x, lane = tid & 63, wave = tid >> 6;
    int bkt = blockIdx.x * 4 + wave;
    if (bkt >= NBK2) return;
    int node = bkt * 64 + lane;
    int v = (node < NN) ? (int)(degrees[node] + 0.5f) : 0;
    for (int d = 1; d < 64; d <<= 1) v += __shfl_xor(v, d, 64);
    if (lane == 0) bcnt[bkt] = v;
}

// ---- exclusive scan of 782 bucket counts -> gbase; init gcur (1 block, 4 elems/thread)
__global__ __launch_bounds__(256) void scan_buckets(const int* __restrict__ bcnt,
                                                    int* __restrict__ gbase,
                                                    int* __restrict__ gcur) {
    __shared__ int wsum[4];
    int tid = threadIdx.x, lane = tid & 63, wid = tid >> 6;
    int v[4], s = 0;
#pragma unroll
    for (int j = 0; j < 4; j++) {
        int idx = tid * 4 + j;
        v[j] = (idx < NBK2) ? bcnt[idx] : 0;
        s += v[j];
    }
    int inc = s;
    for (int d = 1; d < 64; d <<= 1) { int t = __shfl_up(inc, d, 64); if (lane >= d) inc += t; }
    if (lane == 63) wsum[wid] = inc;
    __syncthreads();
    int base = 0;
    for (int w = 0; w < wid; w++) base += wsum[w];
    int ex = base + inc - s;
#pragma unroll
    for (int j = 0; j < 4; j++) {
        int idx = tid * 4 + j;
        if (idx < NBK2) { gbase[idx] = ex; gcur[idx] = ex; }
        ex += v[j];
    }
}

// ---- bin edges into bucket-major 4B records with LDS staging (coalesced writeout);
//      accumulate dist_sum via global atomics (200KB, L2-hot).
// record = dst(16b) | (src&63)<<16
__global__ __launch_bounds__(256) void bin_kernel(const int* __restrict__ ei,
                                                  const float* __restrict__ edist,
                                                  int* __restrict__ gcur,
                                                  unsigned* __restrict__ recs,
                                                  float* __restrict__ dist) {
    __shared__ int cnt[NBK2], off[NBK2], gb[NBK2], c2[NBK2];
    __shared__ int wsum[4];
    __shared__ unsigned stage[CH];
    __shared__ int gtg[CH];
    int tid = threadIdx.x, lane = tid & 63, wid = tid >> 6;
    int e0 = blockIdx.x * CH;
    int nval = EE - e0; if (nval > CH) nval = CH;

    for (int i = tid; i < NBK2; i += 256) { cnt[i] = 0; c2[i] = 0; }
    __syncthreads();
#pragma unroll
    for (int k = 0; k < CH / 256; k++) {
        int e = e0 + k * 256 + tid;
        if (e < EE) atomicAdd(&cnt[ei[e] >> 6], 1);
    }
    __syncthreads();
    // exclusive scan of cnt -> off (4 elems/thread)
    {
        int v[4], s = 0;
#pragma unroll
        for (int j = 0; j < 4; j++) {
            int idx = tid * 4 + j;
            v[j] = (idx < NBK2) ? cnt[idx] : 0;
            s += v[j];
        }
        int inc = s;
        for (int d = 1; d < 64; d <<= 1) { int t = __shfl_up(inc, d, 64); if (lane >= d) inc += t; }
        if (lane == 63) wsum[wid] = inc;
        __syncthreads();
        int base = 0;
        for (int w = 0; w < wid; w++) base += wsum[w];
        int ex = base + inc - s;
#pragma unroll
        for (int j = 0; j < 4; j++) {
            int idx = tid * 4 + j;
            if (idx < NBK2) off[idx] = ex;
            ex += v[j];
        }
    }
    __syncthreads();
    // reserve global ranges
    for (int i = tid; i < NBK2; i += 256) {
        int c = cnt[i];
        gb[i] = c ? atomicAdd(&gcur[i], c) : 0;
    }
    __syncthreads();
    // stage records bucket-major; dist atomics
#pragma unroll
    for (int k = 0; k < CH / 256; k++) {
        int e = e0 + k * 256 + tid;
        if (e < EE) {
            int s = ei[e];
            int d = ei[EE + e];
            atomicAdd(dist + s, edist[e]);
            int b = s >> 6;
            int p = atomicAdd(&c2[b], 1);
            int slot = off[b] + p;
            stage[slot] = (unsigned)d | ((unsigned)(s & 63) << 16);
            gtg[slot] = gb[b] + p;
        }
    }
    __syncthreads();
    // coalesced-run writeout
    for (int i = tid; i < nval; i += 256)
        recs[gtg[i]] = stage[i];
}

// ---- per-bucket LDS aggregation + feat emit.
// block = one 64-node bucket. Per wave: 64 records coalesced, shfl-broadcast, x4-unrolled
// independent gathers + ds_add_f32. agg column-PERMUTED: [r][l]=col 2l, [r][64+l]=col 2l+1.
__global__ __launch_bounds__(256) void aggbucket_kernel(const unsigned short* __restrict__ xbf,
                                                        const unsigned* __restrict__ recs,
                                                        const int* __restrict__ gbase,
                                                        const int* __restrict__ bcnt,
                                                        const float* __restrict__ degrees,
                                                        const float* __restrict__ dist,
                                                        unsigned short* __restrict__ featbf) {
    __shared__ float agg[64][128];   // 32KB
    int tid = threadIdx.x, wave = tid >> 6, lane = tid & 63;
    int bkt = blockIdx.x;
    int st = gbase[bkt], cnt = bcnt[bkt];

    for (int k = tid; k < 64 * 128; k += 256) ((float*)agg)[k] = 0.f;
    __syncthreads();

    for (int base = wave * 64; base < cnt; base += 256) {
        int rem = cnt - base;
        int nv = rem < 64 ? rem : 64;
        unsigned rec = (lane < nv) ? recs[st + base + lane] : 0;
        int j = 0;
        for (; j + 4 <= nv; j += 4) {
            unsigned r0 = (unsigned)__shfl((int)rec, j,     64);
            unsigned r1 = (unsigned)__shfl((int)rec, j + 1, 64);
            unsigned r2 = (unsigned)__shfl((int)rec, j + 2, 64);
            unsigned r3 = (unsigned)__shfl((int)rec, j + 3, 64);
            unsigned x0 = *(const unsigned*)(xbf + (size_t)(r0 & 0xffff) * 128 + lane * 2);
            unsigned x1 = *(const unsigned*)(xbf + (size_t)(r1 & 0xffff) * 128 + lane * 2);
            unsigned x2 = *(const unsigned*)(xbf + (size_t)(r2 & 0xffff) * 128 + lane * 2);
            unsigned x3 = *(const unsigned*)(xbf + (size_t)(r3 & 0xffff) * 128 + lane * 2);
            int n0 = (r0 >> 16) & 63, n1 = (r1 >> 16) & 63, n2 = (r2 >> 16) & 63, n3 = (r3 >> 16) & 63;
            atomicAdd(&agg[n0][lane], bflo(x0));
            atomicAdd(&agg[n0][64 + lane], bfhi(x0));
            atomicAdd(&agg[n1][lane], bflo(x1));
            atomicAdd(&agg[n1][64 + lane], bfhi(x1));
            atomicAdd(&agg[n2][lane], bflo(x2));
            atomicAdd(&agg[n2][64 + lane], bfhi(x2));
            atomicAdd(&agg[n3][lane], bflo(x3));
            atomicAdd(&agg[n3][64 + lane], bfhi(x3));
        }
        for (; j < nv; j++) {
            unsigned r0 = (unsigned)__shfl((int)rec, j, 64);
            unsigned x0 = *(const unsigned*)(xbf + (size_t)(r0 & 0xffff) * 128 + lane * 2);
            int n0 = (r0 >> 16) & 63;
            atomicAdd(&agg[n0][lane], bflo(x0));
            atomicAdd(&agg[n0][64 + lane], bfhi(x0));
        }
    }
    __syncthreads();

    // emit: 64 rows x 4 segs of 32 cols
    int r = tid >> 2, seg = tid & 3;
    int node = bkt * 64 + r;
    if (node >= NN) return;
    float dg = degrees[node];
    float degc = fmaxf(dg, 1.0f);
    float inv = 1.0f / degc;
    unsigned short* row = featbf + (size_t)node * KD;
    // self feature copy: full 32 columns
    const unsigned short* xr = xbf + (size_t)node * 128 + seg * 32;
    uint4 sa = *(const uint4*)(xr);
    uint4 sb = *(const uint4*)(xr + 8);
    uint4 sc = *(const uint4*)(xr + 16);
    uint4 sd = *(const uint4*)(xr + 24);
    *(uint4*)(row + seg * 32)      = sa;
    *(uint4*)(row + seg * 32 + 8)  = sb;
    *(uint4*)(row + seg * 32 + 16) = sc;
    *(uint4*)(row + seg * 32 + 24) = sd;
    // aggregated feature (un-permute)
    unsigned short o[32];
#pragma unroll
    for (int k = 0; k < 32; k++) {
        int c = seg * 32 + k;
        float v = agg[r][((c & 1) << 6) + (c >> 1)] * inv;
        o[k] = f2bf(v);
    }
    *(uint4*)(row + 128 + seg * 32)      = *(const uint4*)(o);
    *(uint4*)(row + 128 + seg * 32 + 8)  = *(const uint4*)(o + 8);
    *(uint4*)(row + 128 + seg * 32 + 16) = *(const uint4*)(o + 16);
    *(uint4*)(row + 128 + seg * 32 + 24) = *(const uint4*)(o + 24);
    if (seg == 3) {
        unsigned short t[16] = {0};
        t[0] = f2bf(dg);
        t[1] = f2bf(dist[node] * inv);
        t[2] = f2bf(1.0f);
        *(uint4*)(row + 256)     = *(const uint4*)(t);
        *(uint4*)(row + 256 + 8) = *(const uint4*)(t + 8);
    }
}

// ---- fused MLP+LN: 32x32x16 MFMA, swapped orientation, in-register h hand-off (unchanged).
__global__ __launch_bounds__(256, 2) void fused_mlp_ln(const unsigned short* __restrict__ featbf,
                                                       const unsigned short* __restrict__ W1Te,
                                                       const unsigned short* __restrict__ W2T,
                                                       const float* __restrict__ x,
                                                       const float* __restrict__ b2,
                                                       const float* __restrict__ gamma,
                                                       const float* __restrict__ beta,
                                                       float* __restrict__ out) {
    __shared__ __align__(16) unsigned char lds[34816 + 16384];
    unsigned char* B1 = lds;            // 64 w1cols x 272 k bf16, XOR-swizzled
    unsigned char* B2 = lds + 34816;    // 128 w2cols x 64 k slice bf16, XOR-swizzled

    int tid = threadIdx.x;
    int wave = tid >> 6, lane = tid & 63;
    int ln = lane & 31, hi = lane >> 5;
    int rowbase = blockIdx.x * 128 + wave * 32;
    int gr = rowbase + ln;
    int xorv = (ln & 7) << 4;

    bf16x8 ffr[17];
    if (gr < NN) {
        const unsigned char* fp = (const unsigned char*)featbf + (size_t)gr * KB + hi * 16;
#pragma unroll
        for (int ks = 0; ks < 17; ks++)
            ffr[ks] = *(const bf16x8*)(fp + ks * 32);
    } else {
#pragma unroll
        for (int ks = 0; ks < 17; ks++) ffr[ks] = (bf16x8)(__bf16)0.0f;
    }

    f32x16 acc2[4] = {};

    for (int ct = 0; ct < 8; ct++) {
        const unsigned short* s1 = W1Te + (size_t)(ct * 64) * KD;
        for (int i = tid; i < 2048; i += 256) {
            int c = i >> 5, slot = i & 31;
            uint4 v = *(const uint4*)(s1 + c * KD + slot * 8);
            *(uint4*)(B1 + ((c * KB + slot * 16) ^ ((c & 7) << 4))) = v;
        }
        if (tid < 128) {
            int c = tid >> 1, half = tid & 1;
            uint4 v = *(const uint4*)(s1 + c * KD + 256 + half * 8);
            *(uint4*)(B1 + ((c * KB + 512 + half * 16) ^ ((c & 7) << 4))) = v;
        }
        const unsigned short* s2 = W2T + ct * 64;
        for (int i = tid; i < 1024; i += 256) {
            int c = i >> 3, s = i & 7;
            uint4 v = *(const uint4*)(s2 + (size_t)c * 512 + s * 8);
            *(uint4*)(B2 + ((c * 128 + s * 16) ^ ((c & 7) << 4))) = v;
        }
        __syncthreads();

        f32x16 acc1[2] = {};
#pragma unroll
        for (int ks = 0; ks < 17; ks++) {
#pragma unroll
            for (int t = 0; t < 2; t++) {
                int col = t * 32 + ln;
                bf16x8 af = *(const bf16x8*)(B1 + ((col * KB + ks * 32 + hi * 16) ^ xorv));
                acc1[t] = __builtin_amdgcn_mfma_f32_32x32x16_bf16(af, ffr[ks], acc1[t], 0, 0, 0);
            }
        }

        unsigned int dw[2][4][2];
#pragma unroll
        for (int t = 0; t < 2; t++)
#pragma unroll
            for (int g = 0; g < 4; g++)
#pragma unroll
                for (int i = 0; i < 2; i++) {
                    float lo = fmaxf(acc1[t][g * 4 + 2 * i], 0.f);
                    float hf = fmaxf(acc1[t][g * 4 + 2 * i + 1], 0.f);
                    dw[t][g][i] = (unsigned int)f2bf(lo) | ((unsigned int)f2bf(hf) << 16);
                }

#pragma unroll
        for (int t = 0; t < 2; t++)
#pragma unroll
            for (int w = 0; w < 2; w++) {
                int ks2 = t * 2 + w;
                unsigned int sL0 = dw[t][2 * w][0],     sL1 = dw[t][2 * w][1];
                unsigned int sH0 = dw[t][2 * w + 1][0], sH1 = dw[t][2 * w + 1][1];
                unsigned int send0 = hi ? sL0 : sH0;
                unsigned int send1 = hi ? sL1 : sH1;
                unsigned int r0 = (unsigned int)__shfl_xor((int)send0, 32, 64);
                unsigned int r1 = (unsigned int)__shfl_xor((int)send1, 32, 64);
                uint4 fd;
                fd.x = hi ? r0 : sL0;
                fd.y = hi ? r1 : sL1;
                fd.z = hi ? sH0 : r0;
                fd.w = hi ? sH1 : r1;
                bf16x8 hfr = __builtin_bit_cast(bf16x8, fd);
#pragma unroll
                for (int at = 0; at < 4; at++) {
                    int col2 = at * 32 + ln;
                    bf16x8 a2 = *(const bf16x8*)(B2 + ((col2 * 128 + ks2 * 32 + hi * 16) ^ xorv));
                    acc2[at] = __builtin_amdgcn_mfma_f32_32x32x16_bf16(a2, hfr, acc2[at], 0, 0, 0);
                }
            }
        __syncthreads();
    }

    bool rok = (gr < NN);
    float sum = 0.f, sq = 0.f;
#pragma unroll
    for (int at = 0; at < 4; at++)
#pragma unroll
        for (int g = 0; g < 4; g++) {
            int c0 = at * 32 + g * 8 + hi * 4;
            float4 bq = *(const float4*)(b2 + c0);
            float4 xq = rok ? *(const float4*)(x + (size_t)gr * 128 + c0) : make_float4(0, 0, 0, 0);
            float vb[4] = { bq.x, bq.y, bq.z, bq.w };
            float vx[4] = { xq.x, xq.y, xq.z, xq.w };
#pragma unroll
            for (int m = 0; m < 4; m++) {
                float v = acc2[at][g * 4 + m] + vb[m] + vx[m];
                acc2[at][g * 4 + m] = v;
                sum += v;
                sq += v * v;
            }
        }
    sum += __shfl_xor(sum, 32, 64);
    sq  += __shfl_xor(sq, 32, 64);
    float mu = sum * (1.0f / 128.0f);
    float var = sq * (1.0f / 128.0f) - mu * mu;
    float rs = rsqrtf(var + LN_EPS);
    if (rok) {
        float* orow = out + (size_t)gr * 128;
#pragma unroll
        for (int at = 0; at < 4; at++)
#pragma unroll
            for (int g = 0; g < 4; g++) {
                int c0 = at * 32 + g * 8 + hi * 4;
                float4 gq = *(const float4*)(gamma + c0);
                float4 be = *(const float4*)(beta + c0);
                float4 o;
                o.x = (acc2[at][g * 4 + 0] - mu) * rs * gq.x + be.x;
                o.y = (acc2[at][g * 4 + 1] - mu) * rs * gq.y + be.y;
                o.z = (acc2[at][g * 4 + 2] - mu) * rs * gq.z + be.z;
                o.w = (acc2[at][g * 4 + 3] - mu) * rs * gq.w + be.w;
                *(float4*)(orow + c0) = o;
            }
    }
}

extern "C" void kernel_launch(void* const* d_in, const int* in_sizes, int n_in,
                              void* d_out, int out_size, void* d_ws, size_t ws_size,
                              hipStream_t stream) {
    const float* x       = (const float*)d_in[0];
    const float* W1      = (const float*)d_in[1];
    const float* b1      = (const float*)d_in[2];
    const float* W2      = (const float*)d_in[3];
    const float* b2      = (const float*)d_in[4];
    const float* gamma   = (const float*)d_in[5];
    const float* beta    = (const float*)d_in[6];
    const int*   ei      = (const int*)d_in[7];
    const float* edist   = (const float*)d_in[8];
    const float* degrees = (const float*)d_in[9];
    float* out = (float*)d_out;

    char* ws = (char*)d_ws;
    size_t off = 0;
    auto alloc = [&](size_t bytes) {
        void* p = ws + off;
        off = (off + bytes + 255) & ~(size_t)255;
        return p;
    };
    unsigned* recs          = (unsigned*)alloc((size_t)EE * 4);     // 2.56 MB
    int* bcnt               = (int*)alloc(NBK2 * 4);
    int* gbase              = (int*)alloc(NBK2 * 4);
    int* gcur               = (int*)alloc(NBK2 * 4);
    float* dist             = (float*)alloc((size_t)NN * 4);
    unsigned short* xbf     = (unsigned short*)alloc((size_t)NN * 128 * 2);
    unsigned short* featbf  = (unsigned short*)alloc((size_t)NN * KD * 2);
    unsigned short* W1Te    = (unsigned short*)alloc((size_t)512 * KD * 2);
    unsigned short* W2T     = (unsigned short*)alloc((size_t)128 * 512 * 2);

    hipMemsetAsync(dist, 0, (size_t)NN * 4, stream);
    cast_x<<<3125, 256, 0, stream>>>(x, xbf);
    prep_weights<<<640, 256, 0, stream>>>(W1, b1, W2, W1Te, W2T);
    hist_kernel<<<(NBK2 + 3) / 4, 256, 0, stream>>>(degrees, bcnt);
    scan_buckets<<<1, 256, 0, stream>>>(bcnt, gbase, gcur);
    bin_kernel<<<(EE + CH - 1) / CH, 256, 0, stream>>>(ei, edist, gcur, recs, dist);
    aggbucket_kernel<<<NBK2, 256, 0, stream>>>(xbf, recs, gbase, bcnt, degrees, dist, featbf);
    fused_mlp_ln<<<(NN + 127) / 128, 256, 0, stream>>>(featbf, W1Te, W2T, x, b2, gamma, beta, out);
}

// Round 8
// 238.039 us; speedup vs baseline: 3.1911x; 3.1911x over previous
//
#include <hip/hip_runtime.h>
#include <hip/hip_bf16.h>

#define NN 50000
#define EE 640000
#define LN_EPS 1e-5f
#define KD 272              // extended K (256 feat + deg + md + 1 + 13 zero pad)
#define KB 544              // bytes per feat/W1 row (KD*2)
#define NBK2 782            // buckets of 64 nodes (src >> 6)
#define CH 4096             // edges per binning block

typedef __bf16 bf16x8 __attribute__((ext_vector_type(8)));
typedef float f32x16 __attribute__((ext_vector_type(16)));

static __device__ __forceinline__ unsigned short f2bf(float f) {
    return __builtin_bit_cast(unsigned short, (__bf16)f);
}
static __device__ __forceinline__ float bflo(unsigned int u) {   // low bf16 of dword
    return __builtin_bit_cast(float, u << 16);
}
static __device__ __forceinline__ float bfhi(unsigned int u) {   // high bf16 of dword
    return __builtin_bit_cast(float, u & 0xffff0000u);
}

// ---- cast x to bf16 (gather source)
__global__ __launch_bounds__(256) void cast_x(const float* __restrict__ x,
                                              unsigned short* __restrict__ xbf) {
    int i = blockIdx.x * 256 + threadIdx.x;          // 8 elems per thread, 3125 blocks exact
    const float4* s = (const float4*)x + (size_t)i * 2;
    float4 a = s[0], b = s[1];
    unsigned short o[8] = { f2bf(a.x), f2bf(a.y), f2bf(a.z), f2bf(a.w),
                            f2bf(b.x), f2bf(b.y), f2bf(b.z), f2bf(b.w) };
    *(uint4*)(xbf + (size_t)i * 8) = *(const uint4*)o;
}

// ---- weight prep: W1Te[c][k] (512 x 272): k<256 = W1[k][c]; 256=W1[256][c]; 257=W1[257][c];
//      258=b1[c]; 259..271=0.  W2T[c][k] (128 x 512) = W2[k][c].
__global__ __launch_bounds__(256) void prep_weights(const float* __restrict__ W1,
                                                    const float* __restrict__ b1,
                                                    const float* __restrict__ W2,
                                                    unsigned short* __restrict__ W1Te,
                                                    unsigned short* __restrict__ W2T) {
    int b = blockIdx.x, tid = threadIdx.x;
    if (b < 512) {
        W1Te[(size_t)b * KD + tid] = f2bf(W1[(size_t)tid * 512 + b]);
        if (tid < 16) {
            float v = 0.f;
            if (tid == 0) v = W1[256 * 512 + b];
            else if (tid == 1) v = W1[257 * 512 + b];
            else if (tid == 2) v = b1[b];
            W1Te[(size_t)b * KD + 256 + tid] = f2bf(v);
        }
    } else {
        int c = b - 512;
        W2T[(size_t)c * 512 + tid]       = f2bf(W2[(size_t)tid * 128 + c]);
        W2T[(size_t)c * 512 + 256 + tid] = f2bf(W2[(size_t)(256 + tid) * 128 + c]);
    }
}

// ---- Prefix scan of int(degrees) over NN elements -> start[]; also seeds bucket cursors ----
__global__ __launch_bounds__(256) void scanA(const float* __restrict__ degrees,
                                             int* __restrict__ blocksum) {
    __shared__ int wsum[4];
    int i = blockIdx.x * 256 + threadIdx.x;
    int v = (i < NN) ? (int)(degrees[i] + 0.5f) : 0;
    int s = v;
    for (int d = 1; d < 64; d <<= 1) s += __shfl_xor(s, d, 64);
    if ((threadIdx.x & 63) == 0) wsum[threadIdx.x >> 6] = s;
    __syncthreads();
    if (threadIdx.x == 0) blocksum[blockIdx.x] = wsum[0] + wsum[1] + wsum[2] + wsum[3];
}

__global__ __launch_bounds__(256) void scanB(const int* __restrict__ blocksum,
                                             int* __restrict__ blockoff, int nb) {
    __shared__ int wsum[4];
    int tid = threadIdx.x;
    int v = (tid < nb) ? blocksum[tid] : 0;
    int lane = tid & 63, wid = tid >> 6;
    int inc = v;
    for (int d = 1; d < 64; d <<= 1) { int t = __shfl_up(inc, d, 64); if (lane >= d) inc += t; }
    if (lane == 63) wsum[wid] = inc;
    __syncthreads();
    int add = 0;
    for (int w = 0; w < wid; w++) add += wsum[w];
    inc += add;
    if (tid < nb) blockoff[tid] = inc - v;   // exclusive
}

__global__ __launch_bounds__(256) void scanC(const float* __restrict__ degrees,
                                             const int* __restrict__ blockoff,
                                             int* __restrict__ start,
                                             int* __restrict__ gcur) {
    __shared__ int wsum[4];
    int tid = threadIdx.x;
    int i = blockIdx.x * 256 + tid;
    int v = (i < NN) ? (int)(degrees[i] + 0.5f) : 0;
    int lane = tid & 63, wid = tid >> 6;
    int inc = v;
    for (int d = 1; d < 64; d <<= 1) { int t = __shfl_up(inc, d, 64); if (lane >= d) inc += t; }
    if (lane == 63) wsum[wid] = inc;
    __syncthreads();
    int add = blockoff[blockIdx.x];
    for (int w = 0; w < wid; w++) add += wsum[w];
    int excl = add + inc - v;
    if (i < NN) {
        start[i] = excl;
        if ((i & 63) == 0) gcur[i >> 6] = excl;   // bucket cursor = CSR start of its first node
    }
}

// ---- bin edges into bucket-major 4B records with LDS staging (coalesced writeout);
//      accumulate dist_sum via global atomics (200KB, L2-hot).
// record = dst(16b) | (src&63)<<16
__global__ __launch_bounds__(256) void bin_kernel(const int* __restrict__ ei,
                                                  const float* __restrict__ edist,
                                                  int* __restrict__ gcur,
                                                  unsigned* __restrict__ recs1,
                                                  float* __restrict__ dist) {
    __shared__ int cnt[NBK2], off[NBK2], gb[NBK2], c2[NBK2];
    __shared__ int wsum[4];
    __shared__ unsigned stage[CH];
    __shared__ int gtg[CH];
    int tid = threadIdx.x, lane = tid & 63, wid = tid >> 6;
    int e0 = blockIdx.x * CH;
    int nval = EE - e0; if (nval > CH) nval = CH;

    for (int i = tid; i < NBK2; i += 256) { cnt[i] = 0; c2[i] = 0; }
    __syncthreads();
#pragma unroll
    for (int k = 0; k < CH / 256; k++) {
        int e = e0 + k * 256 + tid;
        if (e < EE) atomicAdd(&cnt[ei[e] >> 6], 1);
    }
    __syncthreads();
    // exclusive scan of cnt -> off (4 elems/thread)
    {
        int v[4], s = 0;
#pragma unroll
        for (int j = 0; j < 4; j++) {
            int idx = tid * 4 + j;
            v[j] = (idx < NBK2) ? cnt[idx] : 0;
            s += v[j];
        }
        int inc = s;
        for (int d = 1; d < 64; d <<= 1) { int t = __shfl_up(inc, d, 64); if (lane >= d) inc += t; }
        if (lane == 63) wsum[wid] = inc;
        __syncthreads();
        int base = 0;
        for (int w = 0; w < wid; w++) base += wsum[w];
        int ex = base + inc - s;
#pragma unroll
        for (int j = 0; j < 4; j++) {
            int idx = tid * 4 + j;
            if (idx < NBK2) off[idx] = ex;
            ex += v[j];
        }
    }
    __syncthreads();
    // reserve global ranges
    for (int i = tid; i < NBK2; i += 256) {
        int c = cnt[i];
        gb[i] = c ? atomicAdd(&gcur[i], c) : 0;
    }
    __syncthreads();
    // stage records bucket-major; dist atomics
#pragma unroll
    for (int k = 0; k < CH / 256; k++) {
        int e = e0 + k * 256 + tid;
        if (e < EE) {
            int s = ei[e];
            int d = ei[EE + e];
            atomicAdd(dist + s, edist[e]);
            int b = s >> 6;
            int p = atomicAdd(&c2[b], 1);
            int slot = off[b] + p;
            stage[slot] = (unsigned)d | ((unsigned)(s & 63) << 16);
            gtg[slot] = gb[b] + p;
        }
    }
    __syncthreads();
    // coalesced-run writeout
    for (int i = tid; i < nval; i += 256)
        recs1[gtg[i]] = stage[i];
}

// ---- subsort: within each bucket, place records at exact per-node CSR slots (u16 dst)
__global__ __launch_bounds__(256) void subsort_kernel(const unsigned* __restrict__ recs1,
                                                      const int* __restrict__ start,
                                                      unsigned short* __restrict__ recs2) {
    __shared__ int cur[64];
    int bkt = blockIdx.x, tid = threadIdx.x;
    int bstart = start[bkt * 64];
    int bend = (bkt == NBK2 - 1) ? EE : start[(bkt + 1) * 64];
    if (tid < 64) {
        int node = bkt * 64 + tid;
        cur[tid] = (node < NN) ? start[node] : EE;
    }
    __syncthreads();
    for (int i = bstart + tid; i < bend; i += 256) {
        unsigned r = recs1[i];
        int p = atomicAdd(&cur[(r >> 16) & 63], 1);
        recs2[p] = (unsigned short)(r & 0xffffu);
    }
}

// ---- wave-per-node register aggregation (proven R2/R4 structure) + extended feat emit
__global__ __launch_bounds__(256) void aggfeat_kernel(const unsigned short* __restrict__ xbf,
                                                      const int* __restrict__ start,
                                                      const float* __restrict__ degrees,
                                                      const unsigned short* __restrict__ recs2,
                                                      const float* __restrict__ dist,
                                                      unsigned short* __restrict__ featbf) {
    int tid = threadIdx.x;
    int node = blockIdx.x * 4 + (tid >> 6);
    int lane = tid & 63;
    if (node >= NN) return;
    int st = start[node];
    int cnt = (int)(degrees[node] + 0.5f);
    float a0 = 0.f, a1 = 0.f;
    for (int base = 0; base < cnt; base += 64) {
        int rem = cnt - base;
        int nv = rem < 64 ? rem : 64;
        int didx = (lane < nv) ? (int)recs2[st + base + lane] : 0;
        int j = 0;
        for (; j + 4 <= nv; j += 4) {
            int d0 = __shfl(didx, j,     64);
            int d1 = __shfl(didx, j + 1, 64);
            int d2 = __shfl(didx, j + 2, 64);
            int d3 = __shfl(didx, j + 3, 64);
            unsigned x0 = *(const unsigned*)(xbf + (size_t)d0 * 128 + lane * 2);
            unsigned x1 = *(const unsigned*)(xbf + (size_t)d1 * 128 + lane * 2);
            unsigned x2 = *(const unsigned*)(xbf + (size_t)d2 * 128 + lane * 2);
            unsigned x3 = *(const unsigned*)(xbf + (size_t)d3 * 128 + lane * 2);
            a0 += bflo(x0) + bflo(x1) + bflo(x2) + bflo(x3);
            a1 += bfhi(x0) + bfhi(x1) + bfhi(x2) + bfhi(x3);
        }
        for (; j < nv; j++) {
            int dj = __shfl(didx, j, 64);
            unsigned xv = *(const unsigned*)(xbf + (size_t)dj * 128 + lane * 2);
            a0 += bflo(xv);
            a1 += bfhi(xv);
        }
    }
    float dg = degrees[node];
    float degc = fmaxf(dg, 1.0f);
    float inv = 1.0f / degc;
    unsigned short* row = featbf + (size_t)node * KD;
    *(unsigned int*)(row + lane * 2) = *(const unsigned int*)(xbf + (size_t)node * 128 + lane * 2);
    unsigned short o2[2] = { f2bf(a0 * inv), f2bf(a1 * inv) };
    *(unsigned int*)(row + 128 + lane * 2) = *(const unsigned int*)o2;
    if (lane < 4) {
        unsigned short t4[4] = { 0, 0, 0, 0 };
        if (lane == 0) { t4[0] = f2bf(dg); t4[1] = f2bf(dist[node] * inv); t4[2] = f2bf(1.0f); }
        *(uint2*)(row + 256 + lane * 4) = *(const uint2*)t4;
    }
}

// ---- fused MLP+LN: 32x32x16 MFMA, swapped orientation, in-register h hand-off (unchanged).
__global__ __launch_bounds__(256, 2) void fused_mlp_ln(const unsigned short* __restrict__ featbf,
                                                       const unsigned short* __restrict__ W1Te,
                                                       const unsigned short* __restrict__ W2T,
                                                       const float* __restrict__ x,
                                                       const float* __restrict__ b2,
                                                       const float* __restrict__ gamma,
                                                       const float* __restrict__ beta,
                                                       float* __restrict__ out) {
    __shared__ __align__(16) unsigned char lds[34816 + 16384];
    unsigned char* B1 = lds;            // 64 w1cols x 272 k bf16, XOR-swizzled
    unsigned char* B2 = lds + 34816;    // 128 w2cols x 64 k slice bf16, XOR-swizzled

    int tid = threadIdx.x;
    int wave = tid >> 6, lane = tid & 63;
    int ln = lane & 31, hi = lane >> 5;
    int rowbase = blockIdx.x * 128 + wave * 32;
    int gr = rowbase + ln;
    int xorv = (ln & 7) << 4;

    bf16x8 ffr[17];
    if (gr < NN) {
        const unsigned char* fp = (const unsigned char*)featbf + (size_t)gr * KB + hi * 16;
#pragma unroll
        for (int ks = 0; ks < 17; ks++)
            ffr[ks] = *(const bf16x8*)(fp + ks * 32);
    } else {
#pragma unroll
        for (int ks = 0; ks < 17; ks++) ffr[ks] = (bf16x8)(__bf16)0.0f;
    }

    f32x16 acc2[4] = {};

    for (int ct = 0; ct < 8; ct++) {
        const unsigned short* s1 = W1Te + (size_t)(ct * 64) * KD;
        for (int i = tid; i < 2048; i += 256) {
            int c = i >> 5, slot = i & 31;
            uint4 v = *(const uint4*)(s1 + c * KD + slot * 8);
            *(uint4*)(B1 + ((c * KB + slot * 16) ^ ((c & 7) << 4))) = v;
        }
        if (tid < 128) {
            int c = tid >> 1, half = tid & 1;
            uint4 v = *(const uint4*)(s1 + c * KD + 256 + half * 8);
            *(uint4*)(B1 + ((c * KB + 512 + half * 16) ^ ((c & 7) << 4))) = v;
        }
        const unsigned short* s2 = W2T + ct * 64;
        for (int i = tid; i < 1024; i += 256) {
            int c = i >> 3, s = i & 7;
            uint4 v = *(const uint4*)(s2 + (size_t)c * 512 + s * 8);
            *(uint4*)(B2 + ((c * 128 + s * 16) ^ ((c & 7) << 4))) = v;
        }
        __syncthreads();

        f32x16 acc1[2] = {};
#pragma unroll
        for (int ks = 0; ks < 17; ks++) {
#pragma unroll
            for (int t = 0; t < 2; t++) {
                int col = t * 32 + ln;
                bf16x8 af = *(const bf16x8*)(B1 + ((col * KB + ks * 32 + hi * 16) ^ xorv));
                acc1[t] = __builtin_amdgcn_mfma_f32_32x32x16_bf16(af, ffr[ks], acc1[t], 0, 0, 0);
            }
        }

        unsigned int dw[2][4][2];
#pragma unroll
        for (int t = 0; t < 2; t++)
#pragma unroll
            for (int g = 0; g < 4; g++)
#pragma unroll
                for (int i = 0; i < 2; i++) {
                    float lo = fmaxf(acc1[t][g * 4 + 2 * i], 0.f);
                    float hf = fmaxf(acc1[t][g * 4 + 2 * i + 1], 0.f);
                    dw[t][g][i] = (unsigned int)f2bf(lo) | ((unsigned int)f2bf(hf) << 16);
                }

#pragma unroll
        for (int t = 0; t < 2; t++)
#pragma unroll
            for (int w = 0; w < 2; w++) {
                int ks2 = t * 2 + w;
                unsigned int sL0 = dw[t][2 * w][0],     sL1 = dw[t][2 * w][1];
                unsigned int sH0 = dw[t][2 * w + 1][0], sH1 = dw[t][2 * w + 1][1];
                unsigned int send0 = hi ? sL0 : sH0;
                unsigned int send1 = hi ? sL1 : sH1;
                unsigned int r0 = (unsigned int)__shfl_xor((int)send0, 32, 64);
                unsigned int r1 = (unsigned int)__shfl_xor((int)send1, 32, 64);
                uint4 fd;
                fd.x = hi ? r0 : sL0;
                fd.y = hi ? r1 : sL1;
                fd.z = hi ? sH0 : r0;
                fd.w = hi ? sH1 : r1;
                bf16x8 hfr = __builtin_bit_cast(bf16x8, fd);
#pragma unroll
                for (int at = 0; at < 4; at++) {
                    int col2 = at * 32 + ln;
                    bf16x8 a2 = *(const bf16x8*)(B2 + ((col2 * 128 + ks2 * 32 + hi * 16) ^ xorv));
                    acc2[at] = __builtin_amdgcn_mfma_f32_32x32x16_bf16(a2, hfr, acc2[at], 0, 0, 0);
                }
            }
        __syncthreads();
    }

    bool rok = (gr < NN);
    float sum = 0.f, sq = 0.f;
#pragma unroll
    for (int at = 0; at < 4; at++)
#pragma unroll
        for (int g = 0; g < 4; g++) {
            int c0 = at * 32 + g * 8 + hi * 4;
            float4 bq = *(const float4*)(b2 + c0);
            float4 xq = rok ? *(const float4*)(x + (size_t)gr * 128 + c0) : make_float4(0, 0, 0, 0);
            float vb[4] = { bq.x, bq.y, bq.z, bq.w };
            float vx[4] = { xq.x, xq.y, xq.z, xq.w };
#pragma unroll
            for (int m = 0; m < 4; m++) {
                float v = acc2[at][g * 4 + m] + vb[m] + vx[m];
                acc2[at][g * 4 + m] = v;
                sum += v;
                sq += v * v;
            }
        }
    sum += __shfl_xor(sum, 32, 64);
    sq  += __shfl_xor(sq, 32, 64);
    float mu = sum * (1.0f / 128.0f);
    float var = sq * (1.0f / 128.0f) - mu * mu;
    float rs = rsqrtf(var + LN_EPS);
    if (rok) {
        float* orow = out + (size_t)gr * 128;
#pragma unroll
        for (int at = 0; at < 4; at++)
#pragma unroll
            for (int g = 0; g < 4; g++) {
                int c0 = at * 32 + g * 8 + hi * 4;
                float4 gq = *(const float4*)(gamma + c0);
                float4 be = *(const float4*)(beta + c0);
                float4 o;
                o.x = (acc2[at][g * 4 + 0] - mu) * rs * gq.x + be.x;
                o.y = (acc2[at][g * 4 + 1] - mu) * rs * gq.y + be.y;
                o.z = (acc2[at][g * 4 + 2] - mu) * rs * gq.z + be.z;
                o.w = (acc2[at][g * 4 + 3] - mu) * rs * gq.w + be.w;
                *(float4*)(orow + c0) = o;
            }
    }
}

extern "C" void kernel_launch(void* const* d_in, const int* in_sizes, int n_in,
                              void* d_out, int out_size, void* d_ws, size_t ws_size,
                              hipStream_t stream) {
    const float* x       = (const float*)d_in[0];
    const float* W1      = (const float*)d_in[1];
    const float* b1      = (const float*)d_in[2];
    const float* W2      = (const float*)d_in[3];
    const float* b2      = (const float*)d_in[4];
    const float* gamma   = (const float*)d_in[5];
    const float* beta    = (const float*)d_in[6];
    const int*   ei      = (const int*)d_in[7];
    const float* edist   = (const float*)d_in[8];
    const float* degrees = (const float*)d_in[9];
    float* out = (float*)d_out;

    char* ws = (char*)d_ws;
    size_t off = 0;
    auto alloc = [&](size_t bytes) {
        void* p = ws + off;
        off = (off + bytes + 255) & ~(size_t)255;
        return p;
    };
    unsigned* recs1         = (unsigned*)alloc((size_t)EE * 4);          // 2.56 MB
    unsigned short* recs2   = (unsigned short*)alloc((size_t)EE * 2);    // 1.28 MB
    int* start              = (int*)alloc((size_t)NN * 4);
    int* gcur               = (int*)alloc(NBK2 * 4);
    int* blocksum           = (int*)alloc(256 * 4);
    int* blockoff           = (int*)alloc(256 * 4);
    float* dist             = (float*)alloc((size_t)NN * 4);
    unsigned short* xbf     = (unsigned short*)alloc((size_t)NN * 128 * 2);
    unsigned short* featbf  = (unsigned short*)alloc((size_t)NN * KD * 2);
    unsigned short* W1Te    = (unsigned short*)alloc((size_t)512 * KD * 2);
    unsigned short* W2T     = (unsigned short*)alloc((size_t)128 * 512 * 2);

    const int NB = (NN + 255) / 256;   // 196

    hipMemsetAsync(dist, 0, (size_t)NN * 4, stream);
    cast_x<<<3125, 256, 0, stream>>>(x, xbf);
    prep_weights<<<640, 256, 0, stream>>>(W1, b1, W2, W1Te, W2T);
    scanA<<<NB, 256, 0, stream>>>(degrees, blocksum);
    scanB<<<1, 256, 0, stream>>>(blocksum, blockoff, NB);
    scanC<<<NB, 256, 0, stream>>>(degrees, blockoff, start, gcur);
    bin_kernel<<<(EE + CH - 1) / CH, 256, 0, stream>>>(ei, edist, gcur, recs1, dist);
    subsort_kernel<<<NBK2, 256, 0, stream>>>(recs1, start, recs2);
    aggfeat_kernel<<<(NN + 3) / 4, 256, 0, stream>>>(xbf, start, degrees, recs2, dist, featbf);
    fused_mlp_ln<<<(NN + 127) / 128, 256, 0, stream>>>(featbf, W1Te, W2T, x, b2, gamma, beta, out);
}